// Round 3
// baseline (692.230 us; speedup 1.0000x reference)
//
#include <hip/hip_runtime.h>

#define HN 8
#define DH 256
#define HID 2048
#define BB 4
#define SS 2048
#define TT (BB*SS)
#define NQKV 2560      // (H + 2*KV) * D
#define NSLOTS 16384

typedef unsigned short u16;
typedef unsigned int u32;
typedef __bf16 bf16x8 __attribute__((ext_vector_type(8)));
typedef float f32x4 __attribute__((ext_vector_type(4)));
typedef u16 u16x4 __attribute__((ext_vector_type(4)));
typedef u16 u16x8 __attribute__((ext_vector_type(8)));

__device__ __forceinline__ u16 f2bf(float f) {
    u32 u = __builtin_bit_cast(u32, f);
    u = u + 0x7fffu + ((u >> 16) & 1u);   // RNE; inputs are never NaN
    return (u16)(u >> 16);
}
__device__ __forceinline__ float bf2f(u16 h) {
    u32 u = ((u32)h) << 16;
    return __builtin_bit_cast(float, u);
}
__device__ __forceinline__ void gload_lds16(const void* g, void* l) {
    __builtin_amdgcn_global_load_lds((__attribute__((address_space(1))) void*)g,
                                     (__attribute__((address_space(3))) void*)l,
                                     16, 0, 0);
}

// ---------------- fp32 -> bf16 conversion ----------------
__global__ __launch_bounds__(256) void cvt_f32_bf16(const float* __restrict__ in,
                                                    u16* __restrict__ out, long n) {
    long i = ((long)blockIdx.x * blockDim.x + threadIdx.x) * 4;
    long stride = (long)gridDim.x * blockDim.x * 4;
    for (; i < n; i += stride) {
        float4 v = *(const float4*)(in + i);
        u16x4 o4;
        o4[0] = f2bf(v.x); o4[1] = f2bf(v.y); o4[2] = f2bf(v.z); o4[3] = f2bf(v.w);
        *(u16x4*)(out + i) = o4;
    }
}

// ---------------- NT GEMM: C[M,N] = A[M,K] * B[N,K]^T  (m97 recipe) ----------------
template<int OUTBF>
__global__ __launch_bounds__(256) void gemm_nt(const u16* __restrict__ A, const u16* __restrict__ B,
                                               void* __restrict__ C, int M, int N, int K) {
    __shared__ u16 As[128 * 32];
    __shared__ u16 Bs[128 * 32];
    const int tid = threadIdx.x;
    const int lane = tid & 63, w = tid >> 6;
    const int quad = lane >> 4, m16 = lane & 15;
    const int wm = w & 1, wn = w >> 1;
    const int r4 = tid >> 2, c8 = (tid & 3) * 8;
    const long arow = (long)blockIdx.x * 128;
    const long brow = (long)blockIdx.y * 128;

    f32x4 acc[4][4];
#pragma unroll
    for (int i = 0; i < 4; i++)
#pragma unroll
        for (int j = 0; j < 4; j++) acc[i][j] = (f32x4){0.f, 0.f, 0.f, 0.f};

    const u16* Ag = A + (arow + r4) * (long)K + c8;
    const u16* Bg = B + (brow + r4) * (long)K + c8;

    for (int k0 = 0; k0 < K; k0 += 32) {
        __syncthreads();
        gload_lds16(Ag + k0,                 (char*)As + tid * 16);
        gload_lds16(Ag + 64l * K + k0,       (char*)As + 4096 + tid * 16);
        gload_lds16(Bg + k0,                 (char*)Bs + tid * 16);
        gload_lds16(Bg + 64l * K + k0,       (char*)Bs + 4096 + tid * 16);
        __syncthreads();
        bf16x8 af[4], bfr[4];
#pragma unroll
        for (int mi = 0; mi < 4; mi++)
            af[mi] = *(const bf16x8*)(As + (wm * 64 + mi * 16 + m16) * 32 + quad * 8);
#pragma unroll
        for (int ni = 0; ni < 4; ni++)
            bfr[ni] = *(const bf16x8*)(Bs + (wn * 64 + ni * 16 + m16) * 32 + quad * 8);
#pragma unroll
        for (int mi = 0; mi < 4; mi++)
#pragma unroll
            for (int ni = 0; ni < 4; ni++)
                acc[mi][ni] = __builtin_amdgcn_mfma_f32_16x16x32_bf16(af[mi], bfr[ni], acc[mi][ni], 0, 0, 0);
    }
#pragma unroll
    for (int mi = 0; mi < 4; mi++) {
#pragma unroll
        for (int ni = 0; ni < 4; ni++) {
            long col = brow + wn * 64 + ni * 16 + m16;
#pragma unroll
            for (int r = 0; r < 4; r++) {
                long row = arow + wm * 64 + mi * 16 + quad * 4 + r;
                float v = acc[mi][ni][r];
                if (OUTBF) ((u16*)C)[row * N + col] = f2bf(v);
                else       ((float*)C)[row * N + col] = v;
            }
        }
    }
}

// ---------------- RoPE + cache scatter ----------------
__global__ __launch_bounds__(256) void rope_scatter(u16* __restrict__ qkv, const float* __restrict__ cosb,
        const float* __restrict__ sinb, const int* __restrict__ slots,
        u16* __restrict__ kb, float* __restrict__ kc, float* __restrict__ vc) {
    const int t = blockIdx.x, tid = threadIdx.x;
    const long qbase = (long)t * NQKV;
#pragma unroll
    for (int i = 0; i < 4; i++) {
        int idx = tid + i * 256;            // 0..1023 : 8 heads x 128 pairs
        int head = idx >> 7, d = idx & 127;
        long off = qbase + head * DH + d;
        float q1 = bf2f(qkv[off]), q2 = bf2f(qkv[off + 128]);
        float c = cosb[(long)t * 128 + d], s = sinb[(long)t * 128 + d];
        qkv[off]       = f2bf((q1 * c - q2 * s) * 0.0625f);
        qkv[off + 128] = f2bf((q2 * c + q1 * s) * 0.0625f);
    }
    const int slot = slots[t];
    if (tid < 128) {
        int d = tid;
        long off = qbase + HN * DH + d;
        float k1 = bf2f(qkv[off]), k2 = bf2f(qkv[off + 128]);
        float c = cosb[(long)t * 128 + d], s = sinb[(long)t * 128 + d];
        float kn1 = k1 * c - k2 * s, kn2 = k2 * c + k1 * s;
        kb[(long)t * DH + d]       = f2bf(kn1);
        kb[(long)t * DH + d + 128] = f2bf(kn2);
        kc[(long)slot * DH + d]       = kn1;
        kc[(long)slot * DH + d + 128] = kn2;
    }
    {
        int d = tid;
        vc[(long)slot * DH + d] = bf2f(qkv[qbase + (HN + 1) * DH + d]);
    }
}

// ---------------- V transpose: qkv v-slice -> vbt[b][d][s] ----------------
__global__ __launch_bounds__(256) void transpose_v(const u16* __restrict__ qkv, u16* __restrict__ vbt) {
    const int tid = threadIdx.x;
    const int s0 = blockIdx.x * 64, d0 = blockIdx.y * 64, b = blockIdx.z;
#pragma unroll
    for (int i = 0; i < 2; i++) {
        int d = d0 + i * 32 + (tid >> 3);
        int s = s0 + (tid & 7) * 8;
        u16x8 v;
#pragma unroll
        for (int e = 0; e < 8; e++)
            v[e] = qkv[(long)(b * SS + s + e) * NQKV + (HN + 1) * DH + d];
        *(u16x8*)(vbt + ((long)b * DH + d) * SS + s) = v;
    }
}

// ---------------- Flash attention (causal, GQA KV=1) ----------------
// Block = (b, h, 128 q rows) = 4 waves x 32 q rows each (2 row-frags of 16).
// Each K/V LDS fragment read now feeds 2 MFMAs -> LDS-read traffic per FLOP halved,
// tile count halved (staging+barriers halved) vs the 64-row version.
// Double-buffered gload_lds staging with counted vmcnt(8): next tile's loads stay in
// flight across the barrier; L2 latency hides under this tile's compute.
// XCD-balanced pairing: qb = (x<8)? x : 23-x -> residue r gets {r, 15-r} = 68 tiles.
// Swizzle scheme (rule #21, unchanged from R2 which verified):
//   Ks[s][g] holds K[s][g ^ (s&7)]      -> QK read g = (ks*4+quad) ^ (m16&7)
//   Vt[d][g] holds V[d][g ^ ((d>>1)&3)] -> PV read g = quad ^ ((m16>>1)&3)
__global__ __launch_bounds__(256, 2) void flash_attn(const u16* __restrict__ qkv, const u16* __restrict__ kb,
                                                     const u16* __restrict__ vbt, u16* __restrict__ attn) {
    __shared__ u16 Ks[2][32 * 256];    // 2 x 16 KB
    __shared__ u16 Vt[2][256 * 32];    // 2 x 16 KB
    __shared__ u16 Pl[4 * 32 * 40];    // 10 KB (wave-private P round-trip, 32 rows/wave)
    const int tid = threadIdx.x;
    const int lane = tid & 63, w = tid >> 6;
    const int quad = lane >> 4, m16 = lane & 15;
    const int x = blockIdx.x;
    const int qb = (x < 8) ? x : 23 - x;   // pair (r, 15-r) on each XCD residue
    const int h = blockIdx.y, b = blockIdx.z;
    const int qrow_w = qb * 128 + w * 32;

    // staging index decomposition (per thread; 4 gload_lds rounds each for K and V)
    const int krow = tid >> 5, kg = tid & 31, kgs = kg ^ krow;
    const int vrow = tid >> 2, vg = tid & 3,  vgs = vg ^ ((vrow >> 1) & 3);
    const int km7 = m16 & 7;
    const int vcol = (quad ^ ((m16 >> 1) & 3)) * 8;

    bf16x8 aq[2][8];
#pragma unroll
    for (int rf = 0; rf < 2; rf++) {
        const u16* qp = qkv + (long)(b * SS + qrow_w + rf * 16 + m16) * NQKV + h * DH;
#pragma unroll
        for (int ks = 0; ks < 8; ks++)
            aq[rf][ks] = *(const bf16x8*)(qp + ks * 32 + quad * 8);
    }
    f32x4 o[2][16];
#pragma unroll
    for (int rf = 0; rf < 2; rf++)
#pragma unroll
        for (int i = 0; i < 16; i++) o[rf][i] = (f32x4){0.f, 0.f, 0.f, 0.f};
    float m_run[2][4], l_run[2][4];
#pragma unroll
    for (int rf = 0; rf < 2; rf++)
#pragma unroll
        for (int r = 0; r < 4; r++) { m_run[rf][r] = -1e30f; l_run[rf][r] = 0.f; }

    const long kvrow0 = (long)b * SS;
    const u16* vbase = vbt + (long)b * DH * SS;
    const int ntiles = 4 * qb + 4;

    auto STAGE = [&](int bufi, int kv0_) {
#pragma unroll
        for (int i = 0; i < 4; i++) {
            gload_lds16(kb + (kvrow0 + kv0_ + i * 8 + krow) * DH + kgs * 8,
                        (char*)Ks[bufi] + i * 4096 + tid * 16);
            gload_lds16(vbase + (long)(i * 64 + vrow) * SS + kv0_ + vgs * 8,
                        (char*)Vt[bufi] + i * 4096 + tid * 16);
        }
    };

    STAGE(0, 0);                 // prologue: tile 0 -> buf 0 (8 loads in flight)
    for (int it = 0; it < ntiles; it++) {
        const int kv0 = it * 32;
        const int cur = it & 1;
        if (it + 1 < ntiles) {
            STAGE(cur ^ 1, kv0 + 32);                       // +8 loads (next tile)
            asm volatile("s_waitcnt vmcnt(8)" ::: "memory"); // wait this tile's 8 only
        } else {
            asm volatile("s_waitcnt vmcnt(0)" ::: "memory");
        }
        __syncthreads();   // all waves' staged data for tile `it` visible

        if (kv0 <= qrow_w + 31) {   // wave-uniform: skip fully-masked tiles
            const u16* Ksb = Ks[cur];
            const u16* Vtb = Vt[cur];
            // Q K^T : 32x32 scores per wave (q pre-scaled by 1/16)
            f32x4 sc[2][2];
#pragma unroll
            for (int rf = 0; rf < 2; rf++)
#pragma unroll
                for (int n = 0; n < 2; n++) sc[rf][n] = (f32x4){0.f, 0.f, 0.f, 0.f};
            __builtin_amdgcn_s_setprio(1);
#pragma unroll
            for (int ks = 0; ks < 8; ks++)
#pragma unroll
                for (int n = 0; n < 2; n++) {
                    bf16x8 kf = *(const bf16x8*)(Ksb + (n * 16 + m16) * 256 + (((ks * 4 + quad) ^ km7) << 3));
                    sc[0][n] = __builtin_amdgcn_mfma_f32_16x16x32_bf16(aq[0][ks], kf, sc[0][n], 0, 0, 0);
                    sc[1][n] = __builtin_amdgcn_mfma_f32_16x16x32_bf16(aq[1][ks], kf, sc[1][n], 0, 0, 0);
                }
            __builtin_amdgcn_s_setprio(0);
            // causal mask (tiles at/past the wave's q range)
            if (kv0 >= qrow_w) {
#pragma unroll
                for (int rf = 0; rf < 2; rf++) {
                    const int qg = qrow_w + rf * 16 + quad * 4;
#pragma unroll
                    for (int n = 0; n < 2; n++) {
                        int kvg = kv0 + n * 16 + m16;
#pragma unroll
                        for (int r = 0; r < 4; r++)
                            if (kvg > qg + r) sc[rf][n][r] = -1e30f;
                    }
                }
            }
            // online softmax, defer-max (thr=8); rows live in 16-lane groups
            float mx[2][4];
            bool grow = false;
#pragma unroll
            for (int rf = 0; rf < 2; rf++)
#pragma unroll
                for (int r = 0; r < 4; r++) {
                    mx[rf][r] = fmaxf(sc[rf][0][r], sc[rf][1][r]);
                    grow = grow || (mx[rf][r] > m_run[rf][r] + 8.f);
                }
            if (__any((int)grow)) {   // slow path: first tile + rare growth
#pragma unroll
                for (int off = 1; off <= 8; off <<= 1)
#pragma unroll
                    for (int rf = 0; rf < 2; rf++)
#pragma unroll
                        for (int r = 0; r < 4; r++) mx[rf][r] = fmaxf(mx[rf][r], __shfl_xor(mx[rf][r], off));
#pragma unroll
                for (int rf = 0; rf < 2; rf++)
#pragma unroll
                    for (int r = 0; r < 4; r++) {
                        float mn = fmaxf(m_run[rf][r], mx[rf][r]);
                        float alpha = __expf(m_run[rf][r] - mn);
                        m_run[rf][r] = mn;
                        l_run[rf][r] *= alpha;
#pragma unroll
                        for (int nf = 0; nf < 16; nf++) o[rf][nf][r] *= alpha;
                    }
            }
#pragma unroll
            for (int rf = 0; rf < 2; rf++)
#pragma unroll
                for (int n = 0; n < 2; n++)
#pragma unroll
                    for (int r = 0; r < 4; r++) {
                        float p = __expf(sc[rf][n][r] - m_run[rf][r]);   // bounded by e^8
                        sc[rf][n][r] = p;
                        l_run[rf][r] += p;
                    }
            // P: C-layout -> wave-private LDS -> A-layout (no block barrier needed)
#pragma unroll
            for (int rf = 0; rf < 2; rf++)
#pragma unroll
                for (int n = 0; n < 2; n++)
#pragma unroll
                    for (int r = 0; r < 4; r++)
                        Pl[w * 1280 + (rf * 16 + quad * 4 + r) * 40 + n * 16 + m16] = f2bf(sc[rf][n][r]);
            asm volatile("s_waitcnt lgkmcnt(0)" ::: "memory");
            __builtin_amdgcn_sched_barrier(0);
            bf16x8 ap0 = *(const bf16x8*)(Pl + w * 1280 + m16 * 40 + quad * 8);
            bf16x8 ap1 = *(const bf16x8*)(Pl + w * 1280 + (16 + m16) * 40 + quad * 8);
            __builtin_amdgcn_s_setprio(1);
#pragma unroll
            for (int nf = 0; nf < 16; nf++) {
                bf16x8 vf = *(const bf16x8*)(Vtb + (nf * 16 + m16) * 32 + vcol);
                o[0][nf] = __builtin_amdgcn_mfma_f32_16x16x32_bf16(ap0, vf, o[0][nf], 0, 0, 0);
                o[1][nf] = __builtin_amdgcn_mfma_f32_16x16x32_bf16(ap1, vf, o[1][nf], 0, 0, 0);
            }
            __builtin_amdgcn_s_setprio(0);
        }
        __syncthreads();   // reads of buf[cur^1... reads done before next overwrite
    }
    // final: reduce per-lane l partials across the 16-lane row group
#pragma unroll
    for (int off = 1; off <= 8; off <<= 1)
#pragma unroll
        for (int rf = 0; rf < 2; rf++)
#pragma unroll
            for (int r = 0; r < 4; r++) l_run[rf][r] += __shfl_xor(l_run[rf][r], off);
#pragma unroll
    for (int rf = 0; rf < 2; rf++) {
        float inv[4];
#pragma unroll
        for (int r = 0; r < 4; r++) inv[r] = 1.f / l_run[rf][r];
#pragma unroll
        for (int nf = 0; nf < 16; nf++)
#pragma unroll
            for (int r = 0; r < 4; r++) {
                long row = (long)(b * SS + qrow_w + rf * 16 + quad * 4 + r);
                attn[row * (HN * DH) + h * DH + nf * 16 + m16] = f2bf(o[rf][nf][r] * inv[r]);
            }
    }
}

// ---------------- launch ----------------
extern "C" void kernel_launch(void* const* d_in, const int* in_sizes, int n_in,
                              void* d_out, int out_size, void* d_ws, size_t ws_size,
                              hipStream_t stream) {
    (void)in_sizes; (void)n_in; (void)out_size; (void)ws_size;
    const float* hidden = (const float*)d_in[0];
    const float* cosb   = (const float*)d_in[1];
    const float* sinb   = (const float*)d_in[2];
    const int*   slots  = (const int*)d_in[3];
    const float* kc_in  = (const float*)d_in[4];
    const float* vc_in  = (const float*)d_in[5];
    const float* w_qkv  = (const float*)d_in[6];
    const float* w_o    = (const float*)d_in[7];

    float* out    = (float*)d_out;
    float* kc_out = out + (size_t)TT * HID;
    float* vc_out = kc_out + (size_t)NSLOTS * DH;

    char* p = (char*)d_ws;
    u16* hid_b  = (u16*)p;  p += (size_t)TT * HID * 2;     // 33.6 MB
    u16* wqkv_b = (u16*)p;  p += (size_t)NQKV * HID * 2;   // 10.5 MB
    u16* wo_b   = (u16*)p;  p += (size_t)HID * HID * 2;    // 8.4 MB
    u16* kb     = (u16*)p;  p += (size_t)TT * DH * 2;      // 4.2 MB
    u16* vbt    = (u16*)p;  p += (size_t)TT * DH * 2;      // 4.2 MB  [b][d][s]
    u16* attn_b = hid_b;                 // hid_b dead after GEMM1
    u16* qkv_b  = (u16*)d_out;           // out region scratch; dead before GEMM2 writes

    hipMemcpyAsync(kc_out, kc_in, (size_t)NSLOTS * DH * 4, hipMemcpyDeviceToDevice, stream);
    hipMemcpyAsync(vc_out, vc_in, (size_t)NSLOTS * DH * 4, hipMemcpyDeviceToDevice, stream);

    cvt_f32_bf16<<<dim3(2048), dim3(256), 0, stream>>>(hidden, hid_b, (long)TT * HID);
    cvt_f32_bf16<<<dim3(640),  dim3(256), 0, stream>>>(w_qkv, wqkv_b, (long)NQKV * HID);
    cvt_f32_bf16<<<dim3(512),  dim3(256), 0, stream>>>(w_o,   wo_b,   (long)HID * HID);

    gemm_nt<1><<<dim3(TT / 128, NQKV / 128), dim3(256), 0, stream>>>(hid_b, wqkv_b, qkv_b, TT, NQKV, HID);
    rope_scatter<<<dim3(TT), dim3(256), 0, stream>>>(qkv_b, cosb, sinb, slots, kb, kc_out, vc_out);
    transpose_v<<<dim3(SS / 64, DH / 64, BB), dim3(256), 0, stream>>>(qkv_b, vbt);
    flash_attn<<<dim3(SS / 128, HN, BB), dim3(256), 0, stream>>>(qkv_b, kb, vbt, attn_b);
    gemm_nt<0><<<dim3(TT / 128, HID / 128), dim3(256), 0, stream>>>(attn_b, wo_b, out, TT, HID, HID);
}

// Round 5
// 646.417 us; speedup vs baseline: 1.0709x; 1.0709x over previous
//
#include <hip/hip_runtime.h>

#define HN 8
#define DH 256
#define HID 2048
#define BB 4
#define SS 2048
#define TT (BB*SS)
#define NQKV 2560      // (H + 2*KV) * D
#define NSLOTS 16384

typedef unsigned short u16;
typedef unsigned int u32;
typedef __bf16 bf16x8 __attribute__((ext_vector_type(8)));
typedef float f32x4 __attribute__((ext_vector_type(4)));
typedef u16 u16x4 __attribute__((ext_vector_type(4)));
typedef u16 u16x8 __attribute__((ext_vector_type(8)));

__device__ __forceinline__ u16 f2bf(float f) {
    u32 u = __builtin_bit_cast(u32, f);
    u = u + 0x7fffu + ((u >> 16) & 1u);   // RNE; inputs are never NaN
    return (u16)(u >> 16);
}
__device__ __forceinline__ float bf2f(u16 h) {
    u32 u = ((u32)h) << 16;
    return __builtin_bit_cast(float, u);
}
__device__ __forceinline__ void gload_lds16(const void* g, void* l) {
    __builtin_amdgcn_global_load_lds((__attribute__((address_space(1))) void*)g,
                                     (__attribute__((address_space(3))) void*)l,
                                     16, 0, 0);
}
__device__ __forceinline__ u32 cvtpk_bf16(float a, float b) {
    u32 r;
    asm("v_cvt_pk_bf16_f32 %0, %1, %2" : "=v"(r) : "v"(a), "v"(b));
    return r;
}

// ---------------- fp32 -> bf16 conversion ----------------
__global__ __launch_bounds__(256) void cvt_f32_bf16(const float* __restrict__ in,
                                                    u16* __restrict__ out, long n) {
    long i = ((long)blockIdx.x * blockDim.x + threadIdx.x) * 4;
    long stride = (long)gridDim.x * blockDim.x * 4;
    for (; i < n; i += stride) {
        float4 v = *(const float4*)(in + i);
        u16x4 o4;
        o4[0] = f2bf(v.x); o4[1] = f2bf(v.y); o4[2] = f2bf(v.z); o4[3] = f2bf(v.w);
        *(u16x4*)(out + i) = o4;
    }
}

// ---------------- NT GEMM: C[M,N] = A[M,K] * B[N,K]^T  (m97 recipe) ----------------
template<int OUTBF>
__global__ __launch_bounds__(256) void gemm_nt(const u16* __restrict__ A, const u16* __restrict__ B,
                                               void* __restrict__ C, int M, int N, int K) {
    __shared__ u16 As[128 * 32];
    __shared__ u16 Bs[128 * 32];
    const int tid = threadIdx.x;
    const int lane = tid & 63, w = tid >> 6;
    const int quad = lane >> 4, m16 = lane & 15;
    const int wm = w & 1, wn = w >> 1;
    const int r4 = tid >> 2, c8 = (tid & 3) * 8;
    const long arow = (long)blockIdx.x * 128;
    const long brow = (long)blockIdx.y * 128;

    f32x4 acc[4][4];
#pragma unroll
    for (int i = 0; i < 4; i++)
#pragma unroll
        for (int j = 0; j < 4; j++) acc[i][j] = (f32x4){0.f, 0.f, 0.f, 0.f};

    const u16* Ag = A + (arow + r4) * (long)K + c8;
    const u16* Bg = B + (brow + r4) * (long)K + c8;

    for (int k0 = 0; k0 < K; k0 += 32) {
        __syncthreads();
        gload_lds16(Ag + k0,                 (char*)As + tid * 16);
        gload_lds16(Ag + 64l * K + k0,       (char*)As + 4096 + tid * 16);
        gload_lds16(Bg + k0,                 (char*)Bs + tid * 16);
        gload_lds16(Bg + 64l * K + k0,       (char*)Bs + 4096 + tid * 16);
        __syncthreads();
        bf16x8 af[4], bfr[4];
#pragma unroll
        for (int mi = 0; mi < 4; mi++)
            af[mi] = *(const bf16x8*)(As + (wm * 64 + mi * 16 + m16) * 32 + quad * 8);
#pragma unroll
        for (int ni = 0; ni < 4; ni++)
            bfr[ni] = *(const bf16x8*)(Bs + (wn * 64 + ni * 16 + m16) * 32 + quad * 8);
#pragma unroll
        for (int mi = 0; mi < 4; mi++)
#pragma unroll
            for (int ni = 0; ni < 4; ni++)
                acc[mi][ni] = __builtin_amdgcn_mfma_f32_16x16x32_bf16(af[mi], bfr[ni], acc[mi][ni], 0, 0, 0);
    }
#pragma unroll
    for (int mi = 0; mi < 4; mi++) {
#pragma unroll
        for (int ni = 0; ni < 4; ni++) {
            long col = brow + wn * 64 + ni * 16 + m16;
#pragma unroll
            for (int r = 0; r < 4; r++) {
                long row = arow + wm * 64 + mi * 16 + quad * 4 + r;
                float v = acc[mi][ni][r];
                if (OUTBF) ((u16*)C)[row * N + col] = f2bf(v);
                else       ((float*)C)[row * N + col] = v;
            }
        }
    }
}

// ---------------- RoPE + cache scatter ----------------
__global__ __launch_bounds__(256) void rope_scatter(u16* __restrict__ qkv, const float* __restrict__ cosb,
        const float* __restrict__ sinb, const int* __restrict__ slots,
        u16* __restrict__ kb, float* __restrict__ kc, float* __restrict__ vc) {
    const int t = blockIdx.x, tid = threadIdx.x;
    const long qbase = (long)t * NQKV;
#pragma unroll
    for (int i = 0; i < 4; i++) {
        int idx = tid + i * 256;            // 0..1023 : 8 heads x 128 pairs
        int head = idx >> 7, d = idx & 127;
        long off = qbase + head * DH + d;
        float q1 = bf2f(qkv[off]), q2 = bf2f(qkv[off + 128]);
        float c = cosb[(long)t * 128 + d], s = sinb[(long)t * 128 + d];
        qkv[off]       = f2bf((q1 * c - q2 * s) * 0.0625f);
        qkv[off + 128] = f2bf((q2 * c + q1 * s) * 0.0625f);
    }
    const int slot = slots[t];
    if (tid < 128) {
        int d = tid;
        long off = qbase + HN * DH + d;
        float k1 = bf2f(qkv[off]), k2 = bf2f(qkv[off + 128]);
        float c = cosb[(long)t * 128 + d], s = sinb[(long)t * 128 + d];
        float kn1 = k1 * c - k2 * s, kn2 = k2 * c + k1 * s;
        kb[(long)t * DH + d]       = f2bf(kn1);
        kb[(long)t * DH + d + 128] = f2bf(kn2);
        kc[(long)slot * DH + d]       = kn1;
        kc[(long)slot * DH + d + 128] = kn2;
    }
    {
        int d = tid;
        vc[(long)slot * DH + d] = bf2f(qkv[qbase + (HN + 1) * DH + d]);
    }
}

// ---------------- V transpose: qkv v-slice -> vbt[b][d][s] ----------------
__global__ __launch_bounds__(256) void transpose_v(const u16* __restrict__ qkv, u16* __restrict__ vbt) {
    const int tid = threadIdx.x;
    const int s0 = blockIdx.x * 64, d0 = blockIdx.y * 64, b = blockIdx.z;
#pragma unroll
    for (int i = 0; i < 2; i++) {
        int d = d0 + i * 32 + (tid >> 3);
        int s = s0 + (tid & 7) * 8;
        u16x8 v;
#pragma unroll
        for (int e = 0; e < 8; e++)
            v[e] = qkv[(long)(b * SS + s + e) * NQKV + (HN + 1) * DH + d];
        *(u16x8*)(vbt + ((long)b * DH + d) * SS + s) = v;
    }
}

// ---------------- Flash attention (causal, GQA KV=1) ----------------
// R2 geometry (best: 233us): block = (b, h, 64 q rows), 4 waves x 16 rows, kv-tile 32,
// single-buffer gload_lds staging, XCD-balanced qb remap ({31-r,16+r,15-r,r} per residue).
// NEW: swapped QK^T (sc = mfma(K, Q)) + PERMUTED K staging.
//   Ks row s holds K row kv0 + perm(s), perm = swap bits 2,3 of s (i.e. [n][quad][r]->[quad][n][r]).
//   Then lane (quad,m16) holds P[q=m16][actual kv = kv0 + quad*8 + n*4 + r] -- exactly its
//   PV A-fragment range. P->A-frag = 4 v_cvt_pk_bf16_f32, fully in-lane: the Pl LDS
//   round-trip (5KB + 18 DS ops/wave/tile + lgkm drain) is deleted.
// Softmax: q = m16 per lane -> scalar m/l state; row-reduce = xor16,32 (slow path only);
// l reduced once at the end; alpha/inv broadcast to o-rows (quad*4+r) via __shfl.
// Swizzles (rule #21, verified in R2): Ks granule key = s&7 (= krow), Vt key = (d>>1)&3.
__global__ __launch_bounds__(256, 4) void flash_attn(const u16* __restrict__ qkv, const u16* __restrict__ kb,
                                                     const u16* __restrict__ vbt, u16* __restrict__ attn) {
    __shared__ u16 Ks[32 * 256];      // 16 KB (row-permuted + granule-swizzled)
    __shared__ u16 Vt[256 * 32];      // 16 KB (granule-swizzled)
    const int tid = threadIdx.x;
    const int lane = tid & 63, w = tid >> 6;
    const int quad = lane >> 4, m16 = lane & 15;
    const int xr = blockIdx.x & 7, xt = blockIdx.x >> 3;
    const int qb = (xt == 0) ? 31 - xr : (xt == 1) ? 16 + xr : (xt == 2) ? 15 - xr : xr;
    const int h = blockIdx.y, b = blockIdx.z;
    const int qrow_w = qb * 64 + w * 16;

    // staging decomposition. K: LDS row s = i*8 + krow, src row = kv0 + perm(s):
    //   perm(s) = ((i&1)<<4) + ((krow>>2)<<3) + ((i>>1)<<2) + (krow&3)
    const int krow = tid >> 5, kg = tid & 31, kgs = kg ^ krow;
    const int ks_hi = (krow >> 2) << 3, ks_lo = krow & 3;
    const int vrow = tid >> 2, vg = tid & 3,  vgs = vg ^ ((vrow >> 1) & 3);
    const int km7 = m16 & 7;
    const int vcol = (quad ^ ((m16 >> 1) & 3)) * 8;

    bf16x8 aq[8];
    {
        const u16* qp = qkv + (long)(b * SS + qrow_w + m16) * NQKV + h * DH;
#pragma unroll
        for (int ks = 0; ks < 8; ks++)
            aq[ks] = *(const bf16x8*)(qp + ks * 32 + quad * 8);
    }
    f32x4 o[16];
#pragma unroll
    for (int i = 0; i < 16; i++) o[i] = (f32x4){0.f, 0.f, 0.f, 0.f};
    float m_run = -1e30f;   // running max for q row = m16 (row-uniform across quads)
    float l_run = 0.f;      // per-lane partial sum for q row = m16
    const long kvrow0 = (long)b * SS;
    const u16* vbase = vbt + (long)b * DH * SS;
    const int ntiles = 2 * qb + 2;

    for (int it = 0; it < ntiles; it++) {
        const int kv0 = it * 32;
        __syncthreads();   // all waves done reading previous tile's LDS
#pragma unroll
        for (int i = 0; i < 4; i++) {
            const int srcrow = ((i & 1) << 4) + ks_hi + ((i >> 1) << 2) + ks_lo;  // perm(i*8+krow)
            gload_lds16(kb + (kvrow0 + kv0 + srcrow) * DH + kgs * 8,
                        (char*)Ks + i * 4096 + tid * 16);
            gload_lds16(vbase + (long)(i * 64 + vrow) * SS + kv0 + vgs * 8,
                        (char*)Vt + i * 4096 + tid * 16);
        }
        asm volatile("s_waitcnt vmcnt(0)" ::: "memory");
        __syncthreads();   // staging visible to all waves

        if (kv0 <= qrow_w + 15) {   // wave-uniform: skip fully-masked tiles
            // swapped Q K^T : D[kv][q], lane holds q=m16, kv = n*16+quad*4+r (LDS-row space)
            f32x4 sc[2];
            sc[0] = (f32x4){0.f, 0.f, 0.f, 0.f};
            sc[1] = (f32x4){0.f, 0.f, 0.f, 0.f};
            __builtin_amdgcn_s_setprio(1);
#pragma unroll
            for (int ks = 0; ks < 8; ks++)
#pragma unroll
                for (int n = 0; n < 2; n++) {
                    bf16x8 kf = *(const bf16x8*)(Ks + (n * 16 + m16) * 256 + (((ks * 4 + quad) ^ km7) << 3));
                    sc[n] = __builtin_amdgcn_mfma_f32_16x16x32_bf16(kf, aq[ks], sc[n], 0, 0, 0);
                }
            __builtin_amdgcn_s_setprio(0);
            // causal mask: actual kv = kv0 + quad*8 + n*4 + r (perm-staged); q = qrow_w + m16
            if (kv0 >= qb * 64) {
                const int qg = qrow_w + m16;
                const int kvb = kv0 + quad * 8;
#pragma unroll
                for (int n = 0; n < 2; n++)
#pragma unroll
                    for (int r = 0; r < 4; r++)
                        if (kvb + n * 4 + r > qg) sc[n][r] = -1e30f;
            }
            // online softmax, defer-max (thr=8): per-lane 8 values of row q=m16
            float mx = fmaxf(fmaxf(fmaxf(sc[0][0], sc[0][1]), fmaxf(sc[0][2], sc[0][3])),
                             fmaxf(fmaxf(sc[1][0], sc[1][1]), fmaxf(sc[1][2], sc[1][3])));
            if (__any((int)(mx > m_run + 8.f))) {   // slow path: first tile + rare growth
                float mr = fmaxf(mx, __shfl_xor(mx, 16));
                mr = fmaxf(mr, __shfl_xor(mr, 32));
                float mn = fmaxf(m_run, mr);
                float alpha = __expf(m_run - mn);   // row-uniform (for q=m16)
                m_run = mn;
                l_run *= alpha;
                float ar[4];
#pragma unroll
                for (int r = 0; r < 4; r++) ar[r] = __shfl(alpha, quad * 4 + r);  // o rows = quad*4+r
#pragma unroll
                for (int nf = 0; nf < 16; nf++)
#pragma unroll
                    for (int r = 0; r < 4; r++) o[nf][r] *= ar[r];
            }
#pragma unroll
            for (int n = 0; n < 2; n++)
#pragma unroll
                for (int r = 0; r < 4; r++) {
                    float p = __expf(sc[n][r] - m_run);   // bounded by e^8
                    sc[n][r] = p;
                    l_run += p;
                }
            // P -> PV A-frag: in-lane pack (element e = n*4+r matches kv = quad*8+e)
            union { u32 w4[4]; bf16x8 v; } pu;
            pu.w4[0] = cvtpk_bf16(sc[0][0], sc[0][1]);
            pu.w4[1] = cvtpk_bf16(sc[0][2], sc[0][3]);
            pu.w4[2] = cvtpk_bf16(sc[1][0], sc[1][1]);
            pu.w4[3] = cvtpk_bf16(sc[1][2], sc[1][3]);
            __builtin_amdgcn_s_setprio(1);
#pragma unroll
            for (int nf = 0; nf < 16; nf++) {
                bf16x8 vf = *(const bf16x8*)(Vt + (nf * 16 + m16) * 32 + vcol);
                o[nf] = __builtin_amdgcn_mfma_f32_16x16x32_bf16(pu.v, vf, o[nf], 0, 0, 0);
            }
            __builtin_amdgcn_s_setprio(0);
        }
    }
    // final: reduce per-lane l partials across quads (row q=m16), then bcast to o rows
    l_run += __shfl_xor(l_run, 16);
    l_run += __shfl_xor(l_run, 32);
    float invm = 1.f / l_run;
    float ir[4];
#pragma unroll
    for (int r = 0; r < 4; r++) ir[r] = __shfl(invm, quad * 4 + r);
#pragma unroll
    for (int nf = 0; nf < 16; nf++)
#pragma unroll
        for (int r = 0; r < 4; r++) {
            long row = (long)(b * SS + qrow_w + quad * 4 + r);
            attn[row * (HN * DH) + h * DH + nf * 16 + m16] = f2bf(o[nf][r] * ir[r]);
        }
}

// ---------------- launch ----------------
extern "C" void kernel_launch(void* const* d_in, const int* in_sizes, int n_in,
                              void* d_out, int out_size, void* d_ws, size_t ws_size,
                              hipStream_t stream) {
    (void)in_sizes; (void)n_in; (void)out_size; (void)ws_size;
    const float* hidden = (const float*)d_in[0];
    const float* cosb   = (const float*)d_in[1];
    const float* sinb   = (const float*)d_in[2];
    const int*   slots  = (const int*)d_in[3];
    const float* kc_in  = (const float*)d_in[4];
    const float* vc_in  = (const float*)d_in[5];
    const float* w_qkv  = (const float*)d_in[6];
    const float* w_o    = (const float*)d_in[7];

    float* out    = (float*)d_out;
    float* kc_out = out + (size_t)TT * HID;
    float* vc_out = kc_out + (size_t)NSLOTS * DH;

    char* p = (char*)d_ws;
    u16* hid_b  = (u16*)p;  p += (size_t)TT * HID * 2;     // 33.6 MB
    u16* wqkv_b = (u16*)p;  p += (size_t)NQKV * HID * 2;   // 10.5 MB
    u16* wo_b   = (u16*)p;  p += (size_t)HID * HID * 2;    // 8.4 MB
    u16* kb     = (u16*)p;  p += (size_t)TT * DH * 2;      // 4.2 MB
    u16* vbt    = (u16*)p;  p += (size_t)TT * DH * 2;      // 4.2 MB  [b][d][s]
    u16* attn_b = hid_b;                 // hid_b dead after GEMM1
    u16* qkv_b  = (u16*)d_out;           // out region scratch; dead before GEMM2 writes

    hipMemcpyAsync(kc_out, kc_in, (size_t)NSLOTS * DH * 4, hipMemcpyDeviceToDevice, stream);
    hipMemcpyAsync(vc_out, vc_in, (size_t)NSLOTS * DH * 4, hipMemcpyDeviceToDevice, stream);

    cvt_f32_bf16<<<dim3(2048), dim3(256), 0, stream>>>(hidden, hid_b, (long)TT * HID);
    cvt_f32_bf16<<<dim3(640),  dim3(256), 0, stream>>>(w_qkv, wqkv_b, (long)NQKV * HID);
    cvt_f32_bf16<<<dim3(512),  dim3(256), 0, stream>>>(w_o,   wo_b,   (long)HID * HID);

    gemm_nt<1><<<dim3(TT / 128, NQKV / 128), dim3(256), 0, stream>>>(hid_b, wqkv_b, qkv_b, TT, NQKV, HID);
    rope_scatter<<<dim3(TT), dim3(256), 0, stream>>>(qkv_b, cosb, sinb, slots, kb, kc_out, vc_out);
    transpose_v<<<dim3(SS / 64, DH / 64, BB), dim3(256), 0, stream>>>(qkv_b, vbt);
    flash_attn<<<dim3(SS / 64, HN, BB), dim3(256), 0, stream>>>(qkv_b, kb, vbt, attn_b);
    gemm_nt<0><<<dim3(TT / 128, HID / 128), dim3(256), 0, stream>>>(attn_b, wo_b, out, TT, HID, HID);
}